// Round 9
// baseline (393.844 us; speedup 1.0000x reference)
//
#include <hip/hip_runtime.h>
#include <math.h>

// Chamfer loss via MFMA (bf16 error-split), B=4, N=M=8192, D=3.
// d'[m,n] = gn[m] - 2 g[m].p[n] via v_mfma_f32_32x32x16_bf16; K-slots: per
// coord: A=(-2gh,-2gh,-2gl,-2gl) x B=(ph,pl,ph,pl); slots 12/13: (gnh,gnl)x(1,1).
// Min over rows -> row & K mappings cancel; C col = lane&31 (HW-verified).
// Round-9 fix: sched_barrier(0) after each MFMA-pair consume prevents the
// scheduler from hoisting 16 f32x16 results into flight (the round-7/8 spill:
// 1-2 GB of scratch traffic, MfmaUtil ~1%). Max 2 accs live by construction
// AND by schedule.
// ws: mins(256K) | partials | pnP | pnG | packAG | packAP | packBP | packBG.

typedef __bf16 bf16x8 __attribute__((ext_vector_type(8)));
typedef float f32x16 __attribute__((ext_vector_type(16)));

#define BATCH 4
#define NPTS 8192
#define TILES (NPTS / 32)          // 256 tiles per batch-dir
#define THREADS 256
#define WAVES 4
#define NT 4                       // col-tiles per wave
#define COLBLOCKS (NPTS / (32 * NT * WAVES))  // 16
#define MCHUNKS 8
#define TPC (TILES / MCHUNKS)      // 32 m-tiles per chunk
#define ROUNDS (TPC / WAVES)       // 8 rounds, WAVES tiles staged per round
#define RB1 64

// One thread per point: init mins, compute norms, emit A- and B-fragments.
__global__ __launch_bounds__(256) void pack_init_kernel(
    const float* __restrict__ P, const float* __restrict__ G,
    uint4* __restrict__ packAP, uint4* __restrict__ packAG,
    uint4* __restrict__ packBP, uint4* __restrict__ packBG,
    float* __restrict__ pnP, float* __restrict__ pnG,
    unsigned* __restrict__ mins) {
    int i = blockIdx.x * blockDim.x + threadIdx.x;   // [0, 2*B*N)
    if (i >= 2 * BATCH * NPTS) return;
    mins[i] = 0x7F800000u;  // +inf bits
    int set = (i >= BATCH * NPTS);
    int j = set ? i - BATCH * NPTS : i;              // [0, B*N)
    const float* src = set ? G : P;
    float x = src[3 * (size_t)j], y = src[3 * (size_t)j + 1], z = src[3 * (size_t)j + 2];
    float n2 = fmaf(x, x, fmaf(y, y, z * z));
    // 2-way bf16 splits (hi = bf16(v), lo = bf16(v - hi)); residual ~2^-18.
    float xh = (float)(__bf16)x, yh = (float)(__bf16)y, zh = (float)(__bf16)z;
    float xl = x - xh, yl = y - yh, zl = z - zh;
    float nh = (float)(__bf16)n2, nl = n2 - nh;

    bf16x8 a0, a1, b0, b1;
    a0[0] = (__bf16)(-2.f * xh); a0[1] = a0[0];
    a0[2] = (__bf16)(-2.f * xl); a0[3] = a0[2];
    a0[4] = (__bf16)(-2.f * yh); a0[5] = a0[4];
    a0[6] = (__bf16)(-2.f * yl); a0[7] = a0[6];
    a1[0] = (__bf16)(-2.f * zh); a1[1] = a1[0];
    a1[2] = (__bf16)(-2.f * zl); a1[3] = a1[2];
    a1[4] = (__bf16)nh; a1[5] = (__bf16)nl;
    a1[6] = (__bf16)0.f; a1[7] = (__bf16)0.f;

    b0[0] = (__bf16)xh; b0[1] = (__bf16)xl; b0[2] = b0[0]; b0[3] = b0[1];
    b0[4] = (__bf16)yh; b0[5] = (__bf16)yl; b0[6] = b0[4]; b0[7] = b0[5];
    b1[0] = (__bf16)zh; b1[1] = (__bf16)zl; b1[2] = b1[0]; b1[3] = b1[1];
    b1[4] = (__bf16)1.f; b1[5] = (__bf16)1.f;
    b1[6] = (__bf16)0.f; b1[7] = (__bf16)0.f;

    // tile = j>>5, lane&31 = point-in-tile, lanes 0-31 k=0..7, 32-63 k=8..15.
    size_t t64 = ((size_t)(j >> 5)) * 64;
    int l = j & 31;
    uint4* A  = set ? packAG : packAP;
    uint4* Bf = set ? packBG : packBP;
    A[t64 + l]       = __builtin_bit_cast(uint4, a0);
    A[t64 + 32 + l]  = __builtin_bit_cast(uint4, a1);
    Bf[t64 + l]      = __builtin_bit_cast(uint4, b0);
    Bf[t64 + 32 + l] = __builtin_bit_cast(uint4, b1);
    (set ? pnG : pnP)[j] = n2;
}

__device__ __forceinline__ float min16(f32x16 a) {
    float m0 = fminf(a[0], a[1]),  m1 = fminf(a[2], a[3]);
    float m2 = fminf(a[4], a[5]),  m3 = fminf(a[6], a[7]);
    float m4 = fminf(a[8], a[9]),  m5 = fminf(a[10], a[11]);
    float m6 = fminf(a[12], a[13]), m7 = fminf(a[14], a[15]);
    float q0 = fminf(m0, m1), q1 = fminf(m2, m3);
    float q2 = fminf(m4, m5), q3 = fminf(m6, m7);
    return fminf(fminf(q0, q1), fminf(q2, q3));
}

// grid (COLBLOCKS, MCHUNKS, 2*BATCH); block 256 = 4 waves.
// dir0 (z<B): rows=G, cols=P -> d1; dir1: rows=P, cols=G -> d2.
__global__ __launch_bounds__(THREADS, 2) void chamfer_mfma_kernel(
    const uint4* __restrict__ packAP, const uint4* __restrict__ packAG,
    const uint4* __restrict__ packBP, const uint4* __restrict__ packBG,
    const float* __restrict__ pnP, const float* __restrict__ pnG,
    unsigned* __restrict__ mins) {
    int z = blockIdx.z;
    int dir = (z >= BATCH) ? 1 : 0;
    int b = dir ? z - BATCH : z;
    const uint4* Apack = (dir ? packAP : packAG) + (size_t)b * TILES * 64;
    const uint4* Bpack = (dir ? packBG : packBP) + (size_t)b * TILES * 64;
    const float* pn    = (dir ? pnG : pnP) + (size_t)b * NPTS;
    unsigned* out      = mins + (size_t)dir * BATCH * NPTS + (size_t)b * NPTS;

    int tid = threadIdx.x, wave = tid >> 6, lane = tid & 63;
    __shared__ uint4 abuf[2][WAVES][64];   // 8 KB, double-buffered A-tiles

    const f32x16 zero = {0.f, 0.f, 0.f, 0.f, 0.f, 0.f, 0.f, 0.f,
                         0.f, 0.f, 0.f, 0.f, 0.f, 0.f, 0.f, 0.f};

    // B-fragments for this wave's NT col-tiles (resident whole kernel)
    int ct0 = blockIdx.x * (WAVES * NT) + wave * NT;
    bf16x8 bfrag[NT];
#pragma unroll
    for (int t = 0; t < NT; ++t)
        bfrag[t] = __builtin_bit_cast(bf16x8, Bpack[(size_t)(ct0 + t) * 64 + lane]);

    // Element-wise running min per col-tile (64 VGPRs).
    f32x16 rmnv[NT];
#pragma unroll
    for (int t = 0; t < NT; ++t) rmnv[t] = zero + INFINITY;

    int mtile0 = blockIdx.y * TPC;
    // Reg-staged double buffer: wave w stages tile (mtile0 + r*WAVES + w).
    uint4 u = Apack[(size_t)(mtile0 + wave) * 64 + lane];
    abuf[0][wave][lane] = u;
    u = Apack[(size_t)(mtile0 + WAVES + wave) * 64 + lane];
    __syncthreads();

    int cur = 0;
#pragma unroll 1
    for (int r = 0; r < ROUNDS; ++r) {
#pragma unroll
        for (int mt = 0; mt < WAVES; mt += 2) {
            bf16x8 af0 = __builtin_bit_cast(bf16x8, abuf[cur][mt][lane]);
            bf16x8 af1 = __builtin_bit_cast(bf16x8, abuf[cur][mt + 1][lane]);
#pragma unroll
            for (int t = 0; t < NT; ++t) {
                f32x16 acc0 = __builtin_amdgcn_mfma_f32_32x32x16_bf16(
                    af0, bfrag[t], zero, 0, 0, 0);
                f32x16 acc1 = __builtin_amdgcn_mfma_f32_32x32x16_bf16(
                    af1, bfrag[t], zero, 0, 0, 0);
#pragma unroll
                for (int e = 0; e < 16; ++e)
                    rmnv[t][e] = fminf(fminf(acc0[e], acc1[e]), rmnv[t][e]); // v_min3
                // Fence: forbid hoisting later MFMAs above this consume.
                // Without it the scheduler lifts all 16 round-MFMAs into
                // flight -> 256 live VGPRs -> scratch spill (rounds 7/8).
                __builtin_amdgcn_sched_barrier(0);
            }
        }
        if (r + 1 < ROUNDS) abuf[cur ^ 1][wave][lane] = u;     // write-late
        if (r + 2 < ROUNDS)                                    // issue-early
            u = Apack[(size_t)(mtile0 + (r + 2) * WAVES + wave) * 64 + lane];
        __syncthreads();
        cur ^= 1;
    }

    // Final reduce: 16 regs -> 1, then row-halves (lane l vs l+32, same col).
#pragma unroll
    for (int t = 0; t < NT; ++t) {
        float v = min16(rmnv[t]);
        v = fminf(v, __shfl_xor(v, 32, 64));
        int col = (ct0 + t) * 32 + (lane & 31);
        float d = fmaxf(pn[col] + v, 0.f);       // >=0: uint order == float order
        if (lane < 32) atomicMin(&out[col], __float_as_uint(d));
    }
}

// Stage 1: RB1 blocks, each sums a contiguous slice of the mins.
__global__ __launch_bounds__(256) void reduce1_kernel(
    const unsigned* __restrict__ mins, int n1, int n2,
    float* __restrict__ partials) {
    int total = n1 + n2;
    int per_block = total / RB1;               // 1024
    int base = blockIdx.x * per_block;
    float w1 = 0.5f / (float)n1;
    float w2 = 0.5f / (float)n2;

    float acc = 0.0f;
    for (int i = threadIdx.x; i < per_block; i += blockDim.x) {
        int idx = base + i;
        float v = __uint_as_float(mins[idx]);
        float w = (idx < n1) ? w1 : w2;
        acc += w * sqrtf(v);
    }
#pragma unroll
    for (int off = 32; off > 0; off >>= 1)
        acc += __shfl_down(acc, off, 64);

    __shared__ float sdata[4];
    int lane = threadIdx.x & 63;
    int wave = threadIdx.x >> 6;
    if (lane == 0) sdata[wave] = acc;
    __syncthreads();
    if (threadIdx.x == 0)
        partials[blockIdx.x] = sdata[0] + sdata[1] + sdata[2] + sdata[3];
}

__global__ __launch_bounds__(64) void reduce2_kernel(
    const float* __restrict__ partials, float* __restrict__ out) {
    float acc = (threadIdx.x < RB1) ? partials[threadIdx.x] : 0.0f;
#pragma unroll
    for (int off = 32; off > 0; off >>= 1)
        acc += __shfl_down(acc, off, 64);
    if (threadIdx.x == 0) out[0] = acc;
}

extern "C" void kernel_launch(void* const* d_in, const int* in_sizes, int n_in,
                              void* d_out, int out_size, void* d_ws, size_t ws_size,
                              hipStream_t stream) {
    const float* P = (const float*)d_in[0];
    const float* G = (const float*)d_in[1];

    // ws layout
    char* w = (char*)d_ws;
    unsigned* mins   = (unsigned*)w;                      //   0 .. 256K
    float* partials  = (float*)(w + 262144);              // 256 B
    float* pnP       = (float*)(w + 263168);              // 128K
    float* pnG       = (float*)(w + 394240);              // 128K
    uint4* packAG    = (uint4*)(w + 525312);              // 1 MB
    uint4* packAP    = (uint4*)(w + 525312 + 1048576);    // 1 MB
    uint4* packBP    = (uint4*)(w + 525312 + 2 * 1048576);// 1 MB
    uint4* packBG    = (uint4*)(w + 525312 + 3 * 1048576);// 1 MB

    int tot = 2 * BATCH * NPTS;
    pack_init_kernel<<<tot / 256, 256, 0, stream>>>(
        P, G, packAP, packAG, packBP, packBG, pnP, pnG, mins);

    dim3 grid(COLBLOCKS, MCHUNKS, 2 * BATCH);   // (16, 8, 8) = 1024 blocks
    chamfer_mfma_kernel<<<grid, THREADS, 0, stream>>>(
        packAP, packAG, packBP, packBG, pnP, pnG, mins);

    reduce1_kernel<<<RB1, 256, 0, stream>>>(mins, BATCH * NPTS, BATCH * NPTS, partials);
    reduce2_kernel<<<1, 64, 0, stream>>>(partials, (float*)d_out);
}

// Round 10
// 197.421 us; speedup vs baseline: 1.9949x; 1.9949x over previous
//
#include <hip/hip_runtime.h>
#include <math.h>

// Chamfer loss via MFMA (bf16 error-split), B=4, N=M=8192, D=3.
// d'[m,n] = gn[m] - 2 g[m].p[n] via v_mfma_f32_32x32x16_bf16; K-slots: per
// coord: A=(-2gh,-2gh,-2gl,-2gl) x B=(ph,pl,ph,pl); slots 12/13: (gnh,gnl)x(1,1).
// Min over rows -> row & K mappings cancel; C col = lane&31 (HW-verified).
// Round-10 fix: arch-VGPR demand under the 128 half-budget (rounds 7-9 spilled
// ~12 hot regs -> GBs of scratch traffic). Fold each f32x16 acc to 8 floats
// (rows fold freely under the row-min) so the running min is f32x8 per
// col-tile: rmnv8 32 + accs 32 + bfrag 16 + misc ~35 = ~115 < 128.
// ws: mins(256K) | partials | pnP | pnG | packAG | packAP | packBP | packBG.

typedef __bf16 bf16x8 __attribute__((ext_vector_type(8)));
typedef float f32x16 __attribute__((ext_vector_type(16)));
typedef float f32x8 __attribute__((ext_vector_type(8)));

#define BATCH 4
#define NPTS 8192
#define TILES (NPTS / 32)          // 256 tiles per batch-dir
#define THREADS 256
#define WAVES 4
#define NT 4                       // col-tiles per wave
#define COLBLOCKS (NPTS / (32 * NT * WAVES))  // 16
#define MCHUNKS 8
#define TPC (TILES / MCHUNKS)      // 32 m-tiles per chunk
#define ROUNDS (TPC / WAVES)       // 8 rounds, WAVES tiles staged per round
#define RB1 64

// One thread per point: init mins, compute norms, emit A- and B-fragments.
__global__ __launch_bounds__(256) void pack_init_kernel(
    const float* __restrict__ P, const float* __restrict__ G,
    uint4* __restrict__ packAP, uint4* __restrict__ packAG,
    uint4* __restrict__ packBP, uint4* __restrict__ packBG,
    float* __restrict__ pnP, float* __restrict__ pnG,
    unsigned* __restrict__ mins) {
    int i = blockIdx.x * blockDim.x + threadIdx.x;   // [0, 2*B*N)
    if (i >= 2 * BATCH * NPTS) return;
    mins[i] = 0x7F800000u;  // +inf bits
    int set = (i >= BATCH * NPTS);
    int j = set ? i - BATCH * NPTS : i;              // [0, B*N)
    const float* src = set ? G : P;
    float x = src[3 * (size_t)j], y = src[3 * (size_t)j + 1], z = src[3 * (size_t)j + 2];
    float n2 = fmaf(x, x, fmaf(y, y, z * z));
    // 2-way bf16 splits (hi = bf16(v), lo = bf16(v - hi)); residual ~2^-18.
    float xh = (float)(__bf16)x, yh = (float)(__bf16)y, zh = (float)(__bf16)z;
    float xl = x - xh, yl = y - yh, zl = z - zh;
    float nh = (float)(__bf16)n2, nl = n2 - nh;

    bf16x8 a0, a1, b0, b1;
    a0[0] = (__bf16)(-2.f * xh); a0[1] = a0[0];
    a0[2] = (__bf16)(-2.f * xl); a0[3] = a0[2];
    a0[4] = (__bf16)(-2.f * yh); a0[5] = a0[4];
    a0[6] = (__bf16)(-2.f * yl); a0[7] = a0[6];
    a1[0] = (__bf16)(-2.f * zh); a1[1] = a1[0];
    a1[2] = (__bf16)(-2.f * zl); a1[3] = a1[2];
    a1[4] = (__bf16)nh; a1[5] = (__bf16)nl;
    a1[6] = (__bf16)0.f; a1[7] = (__bf16)0.f;

    b0[0] = (__bf16)xh; b0[1] = (__bf16)xl; b0[2] = b0[0]; b0[3] = b0[1];
    b0[4] = (__bf16)yh; b0[5] = (__bf16)yl; b0[6] = b0[4]; b0[7] = b0[5];
    b1[0] = (__bf16)zh; b1[1] = (__bf16)zl; b1[2] = b1[0]; b1[3] = b1[1];
    b1[4] = (__bf16)1.f; b1[5] = (__bf16)1.f;
    b1[6] = (__bf16)0.f; b1[7] = (__bf16)0.f;

    // tile = j>>5, lane&31 = point-in-tile, lanes 0-31 k=0..7, 32-63 k=8..15.
    size_t t64 = ((size_t)(j >> 5)) * 64;
    int l = j & 31;
    uint4* A  = set ? packAG : packAP;
    uint4* Bf = set ? packBG : packBP;
    A[t64 + l]       = __builtin_bit_cast(uint4, a0);
    A[t64 + 32 + l]  = __builtin_bit_cast(uint4, a1);
    Bf[t64 + l]      = __builtin_bit_cast(uint4, b0);
    Bf[t64 + 32 + l] = __builtin_bit_cast(uint4, b1);
    (set ? pnG : pnP)[j] = n2;
}

__device__ __forceinline__ float min8(f32x8 a) {
    float m0 = fminf(a[0], a[1]), m1 = fminf(a[2], a[3]);
    float m2 = fminf(a[4], a[5]), m3 = fminf(a[6], a[7]);
    return fminf(fminf(m0, m1), fminf(m2, m3));
}

// grid (COLBLOCKS, MCHUNKS, 2*BATCH); block 256 = 4 waves.
// dir0 (z<B): rows=G, cols=P -> d1; dir1: rows=P, cols=G -> d2.
__global__ __launch_bounds__(THREADS, 2) void chamfer_mfma_kernel(
    const uint4* __restrict__ packAP, const uint4* __restrict__ packAG,
    const uint4* __restrict__ packBP, const uint4* __restrict__ packBG,
    const float* __restrict__ pnP, const float* __restrict__ pnG,
    unsigned* __restrict__ mins) {
    int z = blockIdx.z;
    int dir = (z >= BATCH) ? 1 : 0;
    int b = dir ? z - BATCH : z;
    const uint4* Apack = (dir ? packAP : packAG) + (size_t)b * TILES * 64;
    const uint4* Bpack = (dir ? packBG : packBP) + (size_t)b * TILES * 64;
    const float* pn    = (dir ? pnG : pnP) + (size_t)b * NPTS;
    unsigned* out      = mins + (size_t)dir * BATCH * NPTS + (size_t)b * NPTS;

    int tid = threadIdx.x, wave = tid >> 6, lane = tid & 63;
    __shared__ uint4 abuf[2][WAVES][64];   // 8 KB, double-buffered A-tiles

    const f32x16 zero = {0.f, 0.f, 0.f, 0.f, 0.f, 0.f, 0.f, 0.f,
                         0.f, 0.f, 0.f, 0.f, 0.f, 0.f, 0.f, 0.f};

    // B-fragments for this wave's NT col-tiles (resident whole kernel)
    int ct0 = blockIdx.x * (WAVES * NT) + wave * NT;
    bf16x8 bfrag[NT];
#pragma unroll
    for (int t = 0; t < NT; ++t)
        bfrag[t] = __builtin_bit_cast(bf16x8, Bpack[(size_t)(ct0 + t) * 64 + lane]);

    // Row-folded running min per col-tile (32 VGPRs total).
    f32x8 rmnv8[NT];
#pragma unroll
    for (int t = 0; t < NT; ++t)
#pragma unroll
        for (int e = 0; e < 8; ++e) rmnv8[t][e] = INFINITY;

    int mtile0 = blockIdx.y * TPC;
    // Reg-staged double buffer: wave w stages tile (mtile0 + r*WAVES + w).
    uint4 u = Apack[(size_t)(mtile0 + wave) * 64 + lane];
    abuf[0][wave][lane] = u;
    u = Apack[(size_t)(mtile0 + WAVES + wave) * 64 + lane];
    __syncthreads();

    int cur = 0;
#pragma unroll 1
    for (int r = 0; r < ROUNDS; ++r) {
#pragma unroll
        for (int mt = 0; mt < WAVES; mt += 2) {
            bf16x8 af0 = __builtin_bit_cast(bf16x8, abuf[cur][mt][lane]);
            bf16x8 af1 = __builtin_bit_cast(bf16x8, abuf[cur][mt + 1][lane]);
#pragma unroll
            for (int t = 0; t < NT; ++t) {
                f32x16 acc0 = __builtin_amdgcn_mfma_f32_32x32x16_bf16(
                    af0, bfrag[t], zero, 0, 0, 0);
                f32x16 acc1 = __builtin_amdgcn_mfma_f32_32x32x16_bf16(
                    af1, bfrag[t], zero, 0, 0, 0);
#pragma unroll
                for (int e = 0; e < 8; ++e) {
                    float f0 = fminf(acc0[e], acc0[e + 8]);   // fold rows
                    float f1 = fminf(acc1[e], acc1[e + 8]);
                    rmnv8[t][e] = fminf(fminf(f0, f1), rmnv8[t][e]);  // v_min3
                }
                // Cap live MFMA results at 2 (live-range fence).
                __builtin_amdgcn_sched_barrier(0);
            }
        }
        if (r + 1 < ROUNDS) abuf[cur ^ 1][wave][lane] = u;     // write-late
        if (r + 2 < ROUNDS)                                    // issue-early
            u = Apack[(size_t)(mtile0 + (r + 2) * WAVES + wave) * 64 + lane];
        __syncthreads();
        cur ^= 1;
    }

    // Final reduce: 8 regs -> 1, then row-halves (lane l vs l+32, same col).
#pragma unroll
    for (int t = 0; t < NT; ++t) {
        float v = min8(rmnv8[t]);
        v = fminf(v, __shfl_xor(v, 32, 64));
        int col = (ct0 + t) * 32 + (lane & 31);
        float d = fmaxf(pn[col] + v, 0.f);       // >=0: uint order == float order
        if (lane < 32) atomicMin(&out[col], __float_as_uint(d));
    }
}

// Stage 1: RB1 blocks, each sums a contiguous slice of the mins.
__global__ __launch_bounds__(256) void reduce1_kernel(
    const unsigned* __restrict__ mins, int n1, int n2,
    float* __restrict__ partials) {
    int total = n1 + n2;
    int per_block = total / RB1;               // 1024
    int base = blockIdx.x * per_block;
    float w1 = 0.5f / (float)n1;
    float w2 = 0.5f / (float)n2;

    float acc = 0.0f;
    for (int i = threadIdx.x; i < per_block; i += blockDim.x) {
        int idx = base + i;
        float v = __uint_as_float(mins[idx]);
        float w = (idx < n1) ? w1 : w2;
        acc += w * sqrtf(v);
    }
#pragma unroll
    for (int off = 32; off > 0; off >>= 1)
        acc += __shfl_down(acc, off, 64);

    __shared__ float sdata[4];
    int lane = threadIdx.x & 63;
    int wave = threadIdx.x >> 6;
    if (lane == 0) sdata[wave] = acc;
    __syncthreads();
    if (threadIdx.x == 0)
        partials[blockIdx.x] = sdata[0] + sdata[1] + sdata[2] + sdata[3];
}

__global__ __launch_bounds__(64) void reduce2_kernel(
    const float* __restrict__ partials, float* __restrict__ out) {
    float acc = (threadIdx.x < RB1) ? partials[threadIdx.x] : 0.0f;
#pragma unroll
    for (int off = 32; off > 0; off >>= 1)
        acc += __shfl_down(acc, off, 64);
    if (threadIdx.x == 0) out[0] = acc;
}

extern "C" void kernel_launch(void* const* d_in, const int* in_sizes, int n_in,
                              void* d_out, int out_size, void* d_ws, size_t ws_size,
                              hipStream_t stream) {
    const float* P = (const float*)d_in[0];
    const float* G = (const float*)d_in[1];

    // ws layout
    char* w = (char*)d_ws;
    unsigned* mins   = (unsigned*)w;                      //   0 .. 256K
    float* partials  = (float*)(w + 262144);              // 256 B
    float* pnP       = (float*)(w + 263168);              // 128K
    float* pnG       = (float*)(w + 394240);              // 128K
    uint4* packAG    = (uint4*)(w + 525312);              // 1 MB
    uint4* packAP    = (uint4*)(w + 525312 + 1048576);    // 1 MB
    uint4* packBP    = (uint4*)(w + 525312 + 2 * 1048576);// 1 MB
    uint4* packBG    = (uint4*)(w + 525312 + 3 * 1048576);// 1 MB

    int tot = 2 * BATCH * NPTS;
    pack_init_kernel<<<tot / 256, 256, 0, stream>>>(
        P, G, packAP, packAG, packBP, packBG, pnP, pnG, mins);

    dim3 grid(COLBLOCKS, MCHUNKS, 2 * BATCH);   // (16, 8, 8) = 1024 blocks
    chamfer_mfma_kernel<<<grid, THREADS, 0, stream>>>(
        packAP, packAG, packBP, packBG, pnP, pnG, mins);

    reduce1_kernel<<<RB1, 256, 0, stream>>>(mins, BATCH * NPTS, BATCH * NPTS, partials);
    reduce2_kernel<<<1, 64, 0, stream>>>(partials, (float*)d_out);
}